// Round 1
// baseline (49.468 us; speedup 1.0000x reference)
//
#include <hip/hip_runtime.h>

// ECT transform: out[b,c,r,t] = sum_{n: index=b, ch=c} sigmoid(SCALE*(lin[r] - x[n]. v[:,t]))
// then normalized by per-(b,c) max over (r,t).

constexpr int T   = 64;
constexpr int RES = 64;
constexpr int MC  = 4;     // MAX_CHANNELS
constexpr float RADIUS = 1.0f;
constexpr float SCALE  = 100.0f;
constexpr float LOG2E  = 1.44269504088896340736f;

#define THREADS 1024
#define WAVES   16
#define RPT     4      // r-values per thread (WAVES * RPT == RES)
#define CHUNK   1024
#define SLICES  4

__global__ void ect_zero(float4* __restrict__ out, int n4) {
    int i = blockIdx.x * blockDim.x + threadIdx.x;
    if (i < n4) out[i] = make_float4(0.f, 0.f, 0.f, 0.f);
}

__global__ __launch_bounds__(THREADS, 8) void ect_main(
    const float* __restrict__ x, const float* __restrict__ v,
    const int* __restrict__ index, const int* __restrict__ channels,
    float* __restrict__ out, int N)
{
    __shared__ float lx0[CHUNK], lx1[CHUNK], lx2[CHUNK];
    __shared__ int l_bounds[2];
    __shared__ int l_cnt;

    const int blk = blockIdx.x;
    const int seg = blk >> 2;          // SLICES == 4
    const int sl  = blk & 3;
    const int b   = seg >> 2;          // MC == 4
    const int c   = seg & 3;

    const int tid  = threadIdx.x;
    const int lane = tid & 63;
    const int wv   = tid >> 6;

    // --- batch range via binary search (index is sorted) ---
    if (tid < 2) {
        int target = b + tid;
        int lo = 0, hi = N;
        while (lo < hi) {
            int mid = (lo + hi) >> 1;
            if (index[mid] < target) lo = mid + 1; else hi = mid;
        }
        l_bounds[tid] = lo;
    }
    __syncthreads();
    const int s0 = l_bounds[0], s1 = l_bounds[1];
    const int len = s1 - s0;
    const int p0 = s0 + (int)(((long long)len * sl) / SLICES);
    const int p1 = s0 + (int)(((long long)len * (sl + 1)) / SLICES);

    // --- per-thread constants: direction (lane -> t), thresholds (wave -> r block) ---
    const float C = SCALE * LOG2E;
    const float v0 = v[0 * T + lane] * C;   // fold C into v so nh comes out pre-scaled
    const float v1 = v[1 * T + lane] * C;
    const float v2 = v[2 * T + lane] * C;
    float klin[RPT];
    #pragma unroll
    for (int k = 0; k < RPT; ++k) {
        int r = wv * RPT + k;
        float lin = -RADIUS + (2.0f * RADIUS) * (float)r / (float)(RES - 1);
        klin[k] = lin * C;
    }

    float acc[RPT] = {0.f, 0.f, 0.f, 0.f};

    for (int base = p0; base < p1; base += CHUNK) {
        const int cnt = min(CHUNK, p1 - base);
        if (tid == 0) l_cnt = 0;
        __syncthreads();

        // --- ballot-compact matching-channel points into LDS ---
        if (tid < cnt) {
            const int pt = base + tid;
            const bool match = (channels[pt] == c);
            unsigned long long mask = __ballot(match);
            int wcnt = __popcll(mask);
            int pos = 0;
            if (lane == 0 && wcnt) pos = atomicAdd(&l_cnt, wcnt);
            pos = __shfl(pos, 0);
            if (match) {
                int off = pos + __popcll(mask & ((1ull << lane) - 1ull));
                lx0[off] = x[pt * 3 + 0];
                lx1[off] = x[pt * 3 + 1];
                lx2[off] = x[pt * 3 + 2];
            }
        }
        __syncthreads();
        const int m = l_cnt;

        // --- hot loop: every thread consumes every compacted point ---
        for (int j = 0; j < m; ++j) {
            const float nhc = lx0[j] * v0 + lx1[j] * v1 + lx2[j] * v2;  // = C * (x.v_t)
            #pragma unroll
            for (int k = 0; k < RPT; ++k) {
                // sigmoid(SCALE*(lin - nh)) = 1 / (1 + 2^(C*nh - C*lin))
                float e = __builtin_amdgcn_exp2f(nhc - klin[k]);
                acc[k] += __builtin_amdgcn_rcpf(1.0f + e);
            }
        }
        __syncthreads();
    }

    float* o = out + (size_t)seg * (RES * T);
    #pragma unroll
    for (int k = 0; k < RPT; ++k) {
        int r = wv * RPT + k;
        atomicAdd(&o[r * T + lane], acc[k]);
    }
}

__global__ __launch_bounds__(THREADS) void ect_norm(float* __restrict__ out) {
    __shared__ float wmax[WAVES];
    __shared__ float sscale;
    const int seg = blockIdx.x;
    float* o = out + (size_t)seg * (RES * T);
    const int tid = threadIdx.x;

    float vals[4];
    float mx = 0.f;
    #pragma unroll
    for (int k = 0; k < 4; ++k) {
        vals[k] = o[tid + k * THREADS];
        mx = fmaxf(mx, vals[k]);
    }
    #pragma unroll
    for (int s = 32; s >= 1; s >>= 1) mx = fmaxf(mx, __shfl_xor(mx, s));
    if ((tid & 63) == 0) wmax[tid >> 6] = mx;
    __syncthreads();
    if (tid == 0) {
        float m2 = wmax[0];
        for (int i = 1; i < WAVES; ++i) m2 = fmaxf(m2, wmax[i]);
        sscale = (m2 > 0.f) ? 1.0f / m2 : 1.0f;
    }
    __syncthreads();
    const float s = sscale;
    #pragma unroll
    for (int k = 0; k < 4; ++k) o[tid + k * THREADS] = vals[k] * s;
}

extern "C" void kernel_launch(void* const* d_in, const int* in_sizes, int n_in,
                              void* d_out, int out_size, void* d_ws, size_t ws_size,
                              hipStream_t stream) {
    const float* x        = (const float*)d_in[0];
    const float* v        = (const float*)d_in[1];
    const int*   index    = (const int*)d_in[2];
    const int*   channels = (const int*)d_in[3];
    float*       out      = (float*)d_out;
    const int N = in_sizes[2];                 // 32768
    const int nseg = out_size / (RES * T);     // 128

    const int n4 = out_size / 4;
    hipLaunchKernelGGL(ect_zero, dim3((n4 + 255) / 256), dim3(256), 0, stream, (float4*)out, n4);
    hipLaunchKernelGGL(ect_main, dim3(nseg * SLICES), dim3(THREADS), 0, stream,
                       x, v, index, channels, out, N);
    hipLaunchKernelGGL(ect_norm, dim3(nseg), dim3(THREADS), 0, stream, out);
}